// Round 2
// baseline (434.845 us; speedup 1.0000x reference)
//
#include <hip/hip_runtime.h>
#include <hip/hip_bf16.h>
#include <cstddef>

#define B_    128
#define D_    2048
#define C_    16522
#define BETA_INV 20.0f      // 1/0.05
#define LSTRIDE 16528       // padded logits row stride (floats)

#define NTILES 1033         // ceil(C/16)
#define NCHUNK 8
#define CHW    2066         // ceil(C/8)

typedef __bf16 bf16;
typedef bf16  bf16x8 __attribute__((ext_vector_type(8)));
typedef float f32x4  __attribute__((ext_vector_type(4)));

// ws layout (bytes):
//   logits : [0, 8462336)                128*16528*4
//   A_pack : [8462336, 8986624)          128*2048*2  bf16 fragment-ordered
//   part   : [8986624, 9052160)          128*8*16*4  row_loss partials
#define WS_APACK_OFF 8462336
#define WS_PART_OFF  8986624

// ---------------------------------------------------------------------------
// pack_a: inputs [128,2048] fp32 -> bf16 in MFMA A-fragment order.
// frag f = mtile*64 + kstep; element tid = f*64 + lane (bf16x8 each).
// A[m = mtile*16 + (lane&15)][k = kstep*32 + (lane>>4)*8 + j]
// ---------------------------------------------------------------------------
__global__ __launch_bounds__(256) void pack_a(const float* __restrict__ inp,
                                              bf16* __restrict__ ap) {
  const int tid  = blockIdx.x * 256 + threadIdx.x;   // 0..32767
  const int lane = tid & 63;
  const int ks   = (tid >> 6) & 63;
  const int mt   = tid >> 12;
  const int row  = mt * 16 + (lane & 15);
  const int col  = ks * 32 + (lane >> 4) * 8;
  const f32x4 v0 = *(const f32x4*)(inp + row * D_ + col);
  const f32x4 v1 = *(const f32x4*)(inp + row * D_ + col + 4);
  bf16x8 b;
  b[0] = (bf16)v0[0]; b[1] = (bf16)v0[1]; b[2] = (bf16)v0[2]; b[3] = (bf16)v0[3];
  b[4] = (bf16)v1[0]; b[5] = (bf16)v1[1]; b[6] = (bf16)v1[2]; b[7] = (bf16)v1[3];
  ((bf16x8*)ap)[tid] = b;
}

// ---------------------------------------------------------------------------
// gemm: 8 waves per block, one 16-row n-tile of em per BLOCK.
// Wave w owns m-tile w (16 of the 128 A rows) -> acc is a single f32x4.
// All 8 waves stream the same 16 em rows (redundant loads hit L1/L2; HBM
// fetch unchanged); wave count rises 1033 -> 8264 (~8 waves/SIMD), which is
// what actually hides the ~900-cyc HBM latency that the 1-deep pipeline
// alone could not (previous version: 1 wave/SIMD, 18% of peak BW).
// Fused fp32 copy-through of em to out_em, distributed one k-chunk per wave,
// nontemporal so out_em writes don't evict em from L3.
// ---------------------------------------------------------------------------
__global__ __launch_bounds__(512, 8) void gemm_logits(
    const bf16*  __restrict__ ap,
    const float* __restrict__ em,
    float*       __restrict__ logits,
    float*       __restrict__ out_em)
{
  const int lane = threadIdx.x & 63;
  const int w    = threadIdx.x >> 6;       // wave id == m-tile index
  const int ml   = lane & 15;
  const int quad = lane >> 4;
  const int n0   = blockIdx.x * 16;
  const int r    = n0 + ml;
  const bool valid = r < C_;

  const float* bp = em + (size_t)(valid ? r : 0) * D_ + quad * 8;
  float*       op = out_em + (size_t)r * D_ + quad * 8;
  const bf16x8* af = (const bf16x8*)ap;

  f32x4 acc = {};

  // prologue: iteration 0 in flight
  f32x4 e0a = *(const f32x4*)(bp);
  f32x4 e0b = *(const f32x4*)(bp + 4);
  bf16x8 A0 = af[(w * 64) * 64 + lane];

  #pragma unroll 3
  for (int ks = 0; ks < 63; ++ks) {
    // prefetch ks+1
    const f32x4 e1a = *(const f32x4*)(bp + (ks + 1) * 32);
    const f32x4 e1b = *(const f32x4*)(bp + (ks + 1) * 32 + 4);
    const bf16x8 A1 = af[(w * 64 + ks + 1) * 64 + lane];
    // copy-through store of current em chunk: one wave per k-step
    if (valid && ((ks & 7) == w)) {
      __builtin_nontemporal_store(e0a, (f32x4*)(op + ks * 32));
      __builtin_nontemporal_store(e0b, (f32x4*)(op + ks * 32 + 4));
    }
    // consume ks
    bf16x8 bv;
    bv[0] = (bf16)e0a[0]; bv[1] = (bf16)e0a[1]; bv[2] = (bf16)e0a[2]; bv[3] = (bf16)e0a[3];
    bv[4] = (bf16)e0b[0]; bv[5] = (bf16)e0b[1]; bv[6] = (bf16)e0b[2]; bv[7] = (bf16)e0b[3];
    acc = __builtin_amdgcn_mfma_f32_16x16x32_bf16(A0, bv, acc, 0, 0, 0);
    // rotate
    e0a = e1a; e0b = e1b;
    A0 = A1;
  }
  // epilogue: iteration 63 (63 & 7 == 7 -> wave 7 stores)
  {
    if (valid && w == 7) {
      __builtin_nontemporal_store(e0a, (f32x4*)(op + 63 * 32));
      __builtin_nontemporal_store(e0b, (f32x4*)(op + 63 * 32 + 4));
    }
    bf16x8 bv;
    bv[0] = (bf16)e0a[0]; bv[1] = (bf16)e0a[1]; bv[2] = (bf16)e0a[2]; bv[3] = (bf16)e0a[3];
    bv[4] = (bf16)e0b[0]; bv[5] = (bf16)e0b[1]; bv[6] = (bf16)e0b[2]; bv[7] = (bf16)e0b[3];
    acc = __builtin_amdgcn_mfma_f32_16x16x32_bf16(A0, bv, acc, 0, 0, 0);
  }

  if (valid) {
    #pragma unroll
    for (int reg = 0; reg < 4; ++reg) {
      const int row = w * 16 + quad * 4 + reg;
      logits[row * LSTRIDE + r] = acc[reg] * BETA_INV;
    }
  }
}

// ---------------------------------------------------------------------------
// row_loss phase A: grid = 128 rows x 8 chunks. Partial online-lse + top-6
// + label logit per chunk -> part[(b*8+c)*16].
// ---------------------------------------------------------------------------
__global__ __launch_bounds__(256) void row_loss_part(
    const float* __restrict__ logits,
    const int*   __restrict__ label,
    float*       __restrict__ part)
{
  const int b = blockIdx.x >> 3;
  const int c = blockIdx.x & 7;
  const int t = threadIdx.x;
  const int lo = c * CHW;
  const int hi = (lo + CHW < C_) ? lo + CHW : C_;
  const float* row = logits + b * LSTRIDE;
  const int y = label[b];

  float m = -INFINITY, s = 0.f, ly = -INFINITY;
  float tv[6]; int ti[6];
  #pragma unroll
  for (int q = 0; q < 6; ++q) { tv[q] = -INFINITY; ti[q] = -1; }

  for (int i = lo + t; i < hi; i += 256) {
    const float v = row[i];
    if (v > m) { s = s * __expf(m - v) + 1.f; m = v; }
    else       { s += __expf(v - m); }
    if (i == y) ly = v;
    if (v > tv[5]) {
      tv[5] = v; ti[5] = i;
      #pragma unroll
      for (int q = 5; q > 0; --q)
        if (tv[q] > tv[q - 1]) {
          const float fv = tv[q]; tv[q] = tv[q - 1]; tv[q - 1] = fv;
          const int   fi = ti[q]; ti[q] = ti[q - 1]; ti[q - 1] = fi;
        }
    }
  }

  __shared__ float rm[256], rs[256];
  __shared__ float cv[1536];
  __shared__ int   ci[1536];
  __shared__ float sly;

  rm[t] = m; rs[t] = s;
  #pragma unroll
  for (int q = 0; q < 6; ++q) { cv[t * 6 + q] = tv[q]; ci[t * 6 + q] = ti[q]; }
  if (t == 0) sly = -INFINITY;
  __syncthreads();
  if (ly != -INFINITY) sly = ly;

  for (int off = 128; off >= 1; off >>= 1) {
    if (t < off) {
      const float m2 = rm[t + off], s2 = rs[t + off];
      const float M = fmaxf(rm[t], m2);
      rs[t] = rs[t] * __expf(rm[t] - M) + s2 * __expf(m2 - M);
      rm[t] = M;
    }
    __syncthreads();
  }

  if (t < 64) {   // wave 0: top-6 of 1536 candidates
    float otv[6]; int oti[6];
    for (int rr = 0; rr < 6; ++rr) {
      float bv = -INFINITY; int bi = -1, bs = -1;
      for (int u = 0; u < 24; ++u) {
        const int slot = t * 24 + u;
        const float v = cv[slot];
        if (v > bv) { bv = v; bi = ci[slot]; bs = slot; }
      }
      #pragma unroll
      for (int off = 32; off >= 1; off >>= 1) {
        const float ov = __shfl_down(bv, off);
        const int   oi = __shfl_down(bi, off);
        const int   os = __shfl_down(bs, off);
        if (ov > bv) { bv = ov; bi = oi; bs = os; }
      }
      bv = __shfl(bv, 0); bi = __shfl(bi, 0); bs = __shfl(bs, 0);
      if (bs >= t * 24 && bs < (t + 1) * 24) cv[bs] = -INFINITY;
      otv[rr] = bv; oti[rr] = bi;
    }
    if (t == 0) {
      float* p = part + (size_t)(b * 8 + c) * 16;
      p[0] = rm[0]; p[1] = rs[0]; p[2] = sly;
      #pragma unroll
      for (int q = 0; q < 6; ++q) { p[4 + q] = otv[q]; ((int*)p)[10 + q] = oti[q]; }
    }
  }
}

// ---------------------------------------------------------------------------
// row_loss merge: 128 blocks x 64 threads. Merge 8 chunk-partials, compute
// loss, atomicAdd into out[0].
// ---------------------------------------------------------------------------
__global__ __launch_bounds__(64) void row_loss_merge(
    const float* __restrict__ part,
    const int*   __restrict__ label,
    float*       __restrict__ out)
{
  const int b = blockIdx.x;
  const int lane = threadIdx.x;
  const int y = label[b];

  float m = -INFINITY, s = 0.f, ly = -INFINITY;
  if (lane < 8) {
    const float* p = part + (size_t)(b * 8 + lane) * 16;
    m = p[0]; s = p[1]; ly = p[2];
  }
  float M = m, LY = ly;
  #pragma unroll
  for (int off = 32; off >= 1; off >>= 1) {
    M  = fmaxf(M,  __shfl_down(M,  off));
    LY = fmaxf(LY, __shfl_down(LY, off));
  }
  M = __shfl(M, 0); LY = __shfl(LY, 0);
  float contrib = (lane < 8) ? s * __expf(m - M) : 0.f;
  #pragma unroll
  for (int off = 32; off >= 1; off >>= 1) contrib += __shfl_down(contrib, off);
  const float S = __shfl(contrib, 0);

  float v = -INFINITY; int idx = -1;
  if (lane < 48) {
    const float* p = part + (size_t)(b * 8 + lane / 6) * 16;
    v   = p[4 + lane % 6];
    idx = ((const int*)p)[10 + lane % 6];
  }
  float stop = 0.f; int intop = 0;
  for (int rr = 0; rr < 6; ++rr) {
    float bv = v; int bi = idx, bl = lane;
    #pragma unroll
    for (int off = 32; off >= 1; off >>= 1) {
      const float ov = __shfl_down(bv, off);
      const int   oi = __shfl_down(bi, off);
      const int   ol = __shfl_down(bl, off);
      if (ov > bv) { bv = ov; bi = oi; bl = ol; }
    }
    bv = __shfl(bv, 0); bi = __shfl(bi, 0); bl = __shfl(bl, 0);
    stop += bv;
    if (bi == y) intop = 1;
    if (lane == bl) v = -INFINITY;
  }

  if (lane == 0) {
    const float lse = M + logf(S);
    const float loss = intop ? (13.f * lse - LY - 2.f * stop)
                             : (15.f * lse - 3.f * LY - 2.f * stop);
    atomicAdd(out, loss * (1.0f / 128.0f));
  }
}

// ---------------------------------------------------------------------------
// em_update: labels staged to LDS. Block i acts only if i is the first
// occurrence of label[i]; walks the duplicate chain sequentially (exact fp32).
// ---------------------------------------------------------------------------
__global__ __launch_bounds__(256) void em_update(
    const float* __restrict__ inp,
    const int*   __restrict__ label,
    const float* __restrict__ em,
    const int*   __restrict__ epoch,
    float*       __restrict__ out_em)
{
  __shared__ int lbl[B_];
  __shared__ float red[4];
  const int t = threadIdx.x;
  if (t < B_) lbl[t] = label[t];
  __syncthreads();

  const int i = blockIdx.x;
  const int y = lbl[i];
  for (int j = 0; j < i; ++j)
    if (lbl[j] == y) return;            // uniform: all threads agree

  const float alpha = 0.01f * (float)epoch[0];
  const int lane = t & 63, wave = t >> 6;

  float r[8];
  #pragma unroll
  for (int u = 0; u < 8; ++u) r[u] = em[(size_t)y * D_ + t + u * 256];

  for (int j = i; j < B_; ++j) {
    if (lbl[j] != y) continue;          // uniform branch
    const float* x = inp + j * D_;
    float ss = 0.f;
    #pragma unroll
    for (int u = 0; u < 8; ++u) {
      r[u] = alpha * r[u] + (1.f - alpha) * x[t + u * 256];
      ss += r[u] * r[u];
    }
    #pragma unroll
    for (int off = 32; off >= 1; off >>= 1) ss += __shfl_down(ss, off);
    if (lane == 0) red[wave] = ss;
    __syncthreads();
    const float inv = 1.f / sqrtf(red[0] + red[1] + red[2] + red[3]);
    #pragma unroll
    for (int u = 0; u < 8; ++u) r[u] *= inv;
    __syncthreads();                    // red[] reused next chain step
  }

  #pragma unroll
  for (int u = 0; u < 8; ++u) out_em[(size_t)y * D_ + t + u * 256] = r[u];
}

// ---------------------------------------------------------------------------
extern "C" void kernel_launch(void* const* d_in, const int* in_sizes, int n_in,
                              void* d_out, int out_size, void* d_ws, size_t ws_size,
                              hipStream_t stream) {
  const float* inp   = (const float*)d_in[0];
  const int*   label = (const int*)d_in[1];
  const float* em    = (const float*)d_in[2];
  const int*   epoch = (const int*)d_in[3];

  float* out    = (float*)d_out;
  float* out_em = out + 1;
  float* logits = (float*)d_ws;
  bf16*  apack  = (bf16*)((char*)d_ws + WS_APACK_OFF);
  float* part   = (float*)((char*)d_ws + WS_PART_OFF);

  hipMemsetAsync(d_out, 0, sizeof(float), stream);   // zero the loss slot

  pack_a        <<<dim3(128),        dim3(256), 0, stream>>>(inp, apack);
  gemm_logits   <<<dim3(NTILES),     dim3(512), 0, stream>>>(apack, em, logits, out_em);
  row_loss_part <<<dim3(B_ * NCHUNK),dim3(256), 0, stream>>>(logits, label, part);
  row_loss_merge<<<dim3(B_),         dim3(64),  0, stream>>>(part, label, out);
  em_update     <<<dim3(B_),         dim3(256), 0, stream>>>(inp, label, em, epoch, out_em);
}

// Round 3
// 387.762 us; speedup vs baseline: 1.1214x; 1.1214x over previous
//
#include <hip/hip_runtime.h>
#include <hip/hip_bf16.h>
#include <cstddef>

#define B_    128
#define D_    2048
#define C_    16522
#define BETA_INV 20.0f      // 1/0.05
#define LSTRIDE 16528       // padded logits row stride (floats)

#define NTILES 1033         // ceil(C/16)
#define NCHUNK 8
#define CHW    2066         // ceil(C/8)

typedef __bf16 bf16;
typedef bf16  bf16x8 __attribute__((ext_vector_type(8)));
typedef float f32x4  __attribute__((ext_vector_type(4)));

// ws layout (bytes):
//   logits : [0, 8462336)                128*16528*4
//   A_pack : [8462336, 8986624)          128*2048*2  bf16 fragment-ordered
//   part   : [8986624, 9052160)          128*8*16*4  row_loss partials
#define WS_APACK_OFF 8462336
#define WS_PART_OFF  8986624

// ---------------------------------------------------------------------------
// pack_a: inputs [128,2048] fp32 -> bf16 in MFMA A-fragment order.
// frag f = mtile*64 + kstep; element tid = f*64 + lane (bf16x8 each).
// A[m = mtile*16 + (lane&15)][k = kstep*32 + (lane>>4)*8 + j]
// ---------------------------------------------------------------------------
__global__ __launch_bounds__(256) void pack_a(const float* __restrict__ inp,
                                              bf16* __restrict__ ap) {
  const int tid  = blockIdx.x * 256 + threadIdx.x;   // 0..32767
  const int lane = tid & 63;
  const int ks   = (tid >> 6) & 63;
  const int mt   = tid >> 12;
  const int row  = mt * 16 + (lane & 15);
  const int col  = ks * 32 + (lane >> 4) * 8;
  const f32x4 v0 = *(const f32x4*)(inp + row * D_ + col);
  const f32x4 v1 = *(const f32x4*)(inp + row * D_ + col + 4);
  bf16x8 b;
  b[0] = (bf16)v0[0]; b[1] = (bf16)v0[1]; b[2] = (bf16)v0[2]; b[3] = (bf16)v0[3];
  b[4] = (bf16)v1[0]; b[5] = (bf16)v1[1]; b[6] = (bf16)v1[2]; b[7] = (bf16)v1[3];
  ((bf16x8*)ap)[tid] = b;
}

// ---------------------------------------------------------------------------
// gemm: 4 waves per block, one 16-row n-tile of em per BLOCK.
// Wave w owns m-tiles {w, w+4} -> acc is 2 f32x4.
// 2-DEEP software pipeline with PLAIN cached stores. Rationale (round-2
// post-mortem): vmcnt retires in issue order and stores share vmcnt with
// loads, so a store issued in iteration t blocks consumption of loads
// issued >= t until the store completes. 1-deep gave stores only one
// iteration of slack (round 0: L2-store-bound at 18% BW); nontemporal made
// completion ~900cyc (round 2: worse + partial-line RMW doubled WRITE_SIZE).
// 2-deep gives loads AND stores two iterations (~2x900cyc) of slack.
// Store distribution (ks&3)==w: exactly one wave writes each k-chunk.
// ---------------------------------------------------------------------------
__global__ __launch_bounds__(256, 4) void gemm_logits(
    const bf16*  __restrict__ ap,
    const float* __restrict__ em,
    float*       __restrict__ logits,
    float*       __restrict__ out_em)
{
  const int lane = threadIdx.x & 63;
  const int w    = threadIdx.x >> 6;       // wave id 0..3
  const int ml   = lane & 15;
  const int quad = lane >> 4;
  const int n0   = blockIdx.x * 16;
  const int r    = n0 + ml;
  const bool valid = r < C_;

  const float* bp = em + (size_t)(valid ? r : 0) * D_ + quad * 8;
  float*       op = out_em + (size_t)r * D_ + quad * 8;
  const bf16x8* af = (const bf16x8*)ap;
  const int mt0 = w, mt1 = w + 4;

  f32x4 acc0 = {}, acc1 = {};

  // prologue: iterations 0 and 1 in flight
  f32x4 e0a = *(const f32x4*)(bp);
  f32x4 e0b = *(const f32x4*)(bp + 4);
  bf16x8 A00 = af[(mt0 * 64 + 0) * 64 + lane];
  bf16x8 A10 = af[(mt1 * 64 + 0) * 64 + lane];
  f32x4 e1a = *(const f32x4*)(bp + 32);
  f32x4 e1b = *(const f32x4*)(bp + 36);
  bf16x8 A01 = af[(mt0 * 64 + 1) * 64 + lane];
  bf16x8 A11 = af[(mt1 * 64 + 1) * 64 + lane];

  #pragma unroll 2
  for (int ks = 0; ks < 62; ++ks) {
    // prefetch ks+2
    const f32x4 e2a = *(const f32x4*)(bp + (ks + 2) * 32);
    const f32x4 e2b = *(const f32x4*)(bp + (ks + 2) * 32 + 4);
    const bf16x8 A02 = af[(mt0 * 64 + ks + 2) * 64 + lane];
    const bf16x8 A12 = af[(mt1 * 64 + ks + 2) * 64 + lane];
    // copy-through store of current em chunk: one wave per k-step
    if (valid && ((ks & 3) == w)) {
      *(f32x4*)(op + ks * 32)     = e0a;
      *(f32x4*)(op + ks * 32 + 4) = e0b;
    }
    // consume ks
    bf16x8 bv;
    bv[0] = (bf16)e0a[0]; bv[1] = (bf16)e0a[1]; bv[2] = (bf16)e0a[2]; bv[3] = (bf16)e0a[3];
    bv[4] = (bf16)e0b[0]; bv[5] = (bf16)e0b[1]; bv[6] = (bf16)e0b[2]; bv[7] = (bf16)e0b[3];
    acc0 = __builtin_amdgcn_mfma_f32_16x16x32_bf16(A00, bv, acc0, 0, 0, 0);
    acc1 = __builtin_amdgcn_mfma_f32_16x16x32_bf16(A10, bv, acc1, 0, 0, 0);
    // rotate
    e0a = e1a; e0b = e1b; e1a = e2a; e1b = e2b;
    A00 = A01; A01 = A02; A10 = A11; A11 = A12;
  }
  // epilogue ks=62 (62&3 == 2 -> wave 2 stores)
  {
    if (valid && w == 2) {
      *(f32x4*)(op + 62 * 32)     = e0a;
      *(f32x4*)(op + 62 * 32 + 4) = e0b;
    }
    bf16x8 bv;
    bv[0] = (bf16)e0a[0]; bv[1] = (bf16)e0a[1]; bv[2] = (bf16)e0a[2]; bv[3] = (bf16)e0a[3];
    bv[4] = (bf16)e0b[0]; bv[5] = (bf16)e0b[1]; bv[6] = (bf16)e0b[2]; bv[7] = (bf16)e0b[3];
    acc0 = __builtin_amdgcn_mfma_f32_16x16x32_bf16(A00, bv, acc0, 0, 0, 0);
    acc1 = __builtin_amdgcn_mfma_f32_16x16x32_bf16(A10, bv, acc1, 0, 0, 0);
  }
  // epilogue ks=63 (63&3 == 3 -> wave 3 stores)
  {
    if (valid && w == 3) {
      *(f32x4*)(op + 63 * 32)     = e1a;
      *(f32x4*)(op + 63 * 32 + 4) = e1b;
    }
    bf16x8 bv;
    bv[0] = (bf16)e1a[0]; bv[1] = (bf16)e1a[1]; bv[2] = (bf16)e1a[2]; bv[3] = (bf16)e1a[3];
    bv[4] = (bf16)e1b[0]; bv[5] = (bf16)e1b[1]; bv[6] = (bf16)e1b[2]; bv[7] = (bf16)e1b[3];
    acc0 = __builtin_amdgcn_mfma_f32_16x16x32_bf16(A01, bv, acc0, 0, 0, 0);
    acc1 = __builtin_amdgcn_mfma_f32_16x16x32_bf16(A11, bv, acc1, 0, 0, 0);
  }

  if (valid) {
    #pragma unroll
    for (int reg = 0; reg < 4; ++reg) {
      const int row0 = mt0 * 16 + quad * 4 + reg;
      const int row1 = mt1 * 16 + quad * 4 + reg;
      logits[row0 * LSTRIDE + r] = acc0[reg] * BETA_INV;
      logits[row1 * LSTRIDE + r] = acc1[reg] * BETA_INV;
    }
  }
}

// ---------------------------------------------------------------------------
// row_loss phase A: grid = 128 rows x 8 chunks. Partial online-lse + top-6
// + label logit per chunk -> part[(b*8+c)*16].
// ---------------------------------------------------------------------------
__global__ __launch_bounds__(256) void row_loss_part(
    const float* __restrict__ logits,
    const int*   __restrict__ label,
    float*       __restrict__ part)
{
  const int b = blockIdx.x >> 3;
  const int c = blockIdx.x & 7;
  const int t = threadIdx.x;
  const int lo = c * CHW;
  const int hi = (lo + CHW < C_) ? lo + CHW : C_;
  const float* row = logits + b * LSTRIDE;
  const int y = label[b];

  float m = -INFINITY, s = 0.f, ly = -INFINITY;
  float tv[6]; int ti[6];
  #pragma unroll
  for (int q = 0; q < 6; ++q) { tv[q] = -INFINITY; ti[q] = -1; }

  for (int i = lo + t; i < hi; i += 256) {
    const float v = row[i];
    if (v > m) { s = s * __expf(m - v) + 1.f; m = v; }
    else       { s += __expf(v - m); }
    if (i == y) ly = v;
    if (v > tv[5]) {
      tv[5] = v; ti[5] = i;
      #pragma unroll
      for (int q = 5; q > 0; --q)
        if (tv[q] > tv[q - 1]) {
          const float fv = tv[q]; tv[q] = tv[q - 1]; tv[q - 1] = fv;
          const int   fi = ti[q]; ti[q] = ti[q - 1]; ti[q - 1] = fi;
        }
    }
  }

  __shared__ float rm[256], rs[256];
  __shared__ float cv[1536];
  __shared__ int   ci[1536];
  __shared__ float sly;

  rm[t] = m; rs[t] = s;
  #pragma unroll
  for (int q = 0; q < 6; ++q) { cv[t * 6 + q] = tv[q]; ci[t * 6 + q] = ti[q]; }
  if (t == 0) sly = -INFINITY;
  __syncthreads();
  if (ly != -INFINITY) sly = ly;

  for (int off = 128; off >= 1; off >>= 1) {
    if (t < off) {
      const float m2 = rm[t + off], s2 = rs[t + off];
      const float M = fmaxf(rm[t], m2);
      rs[t] = rs[t] * __expf(rm[t] - M) + s2 * __expf(m2 - M);
      rm[t] = M;
    }
    __syncthreads();
  }

  if (t < 64) {   // wave 0: top-6 of 1536 candidates
    float otv[6]; int oti[6];
    for (int rr = 0; rr < 6; ++rr) {
      float bv = -INFINITY; int bi = -1, bs = -1;
      for (int u = 0; u < 24; ++u) {
        const int slot = t * 24 + u;
        const float v = cv[slot];
        if (v > bv) { bv = v; bi = ci[slot]; bs = slot; }
      }
      #pragma unroll
      for (int off = 32; off >= 1; off >>= 1) {
        const float ov = __shfl_down(bv, off);
        const int   oi = __shfl_down(bi, off);
        const int   os = __shfl_down(bs, off);
        if (ov > bv) { bv = ov; bi = oi; bs = os; }
      }
      bv = __shfl(bv, 0); bi = __shfl(bi, 0); bs = __shfl(bs, 0);
      if (bs >= t * 24 && bs < (t + 1) * 24) cv[bs] = -INFINITY;
      otv[rr] = bv; oti[rr] = bi;
    }
    if (t == 0) {
      float* p = part + (size_t)(b * 8 + c) * 16;
      p[0] = rm[0]; p[1] = rs[0]; p[2] = sly;
      #pragma unroll
      for (int q = 0; q < 6; ++q) { p[4 + q] = otv[q]; ((int*)p)[10 + q] = oti[q]; }
    }
  }
}

// ---------------------------------------------------------------------------
// row_loss merge: 128 blocks x 64 threads. Merge 8 chunk-partials, compute
// loss, atomicAdd into out[0].
// ---------------------------------------------------------------------------
__global__ __launch_bounds__(64) void row_loss_merge(
    const float* __restrict__ part,
    const int*   __restrict__ label,
    float*       __restrict__ out)
{
  const int b = blockIdx.x;
  const int lane = threadIdx.x;
  const int y = label[b];

  float m = -INFINITY, s = 0.f, ly = -INFINITY;
  if (lane < 8) {
    const float* p = part + (size_t)(b * 8 + lane) * 16;
    m = p[0]; s = p[1]; ly = p[2];
  }
  float M = m, LY = ly;
  #pragma unroll
  for (int off = 32; off >= 1; off >>= 1) {
    M  = fmaxf(M,  __shfl_down(M,  off));
    LY = fmaxf(LY, __shfl_down(LY, off));
  }
  M = __shfl(M, 0); LY = __shfl(LY, 0);
  float contrib = (lane < 8) ? s * __expf(m - M) : 0.f;
  #pragma unroll
  for (int off = 32; off >= 1; off >>= 1) contrib += __shfl_down(contrib, off);
  const float S = __shfl(contrib, 0);

  float v = -INFINITY; int idx = -1;
  if (lane < 48) {
    const float* p = part + (size_t)(b * 8 + lane / 6) * 16;
    v   = p[4 + lane % 6];
    idx = ((const int*)p)[10 + lane % 6];
  }
  float stop = 0.f; int intop = 0;
  for (int rr = 0; rr < 6; ++rr) {
    float bv = v; int bi = idx, bl = lane;
    #pragma unroll
    for (int off = 32; off >= 1; off >>= 1) {
      const float ov = __shfl_down(bv, off);
      const int   oi = __shfl_down(bi, off);
      const int   ol = __shfl_down(bl, off);
      if (ov > bv) { bv = ov; bi = oi; bl = ol; }
    }
    bv = __shfl(bv, 0); bi = __shfl(bi, 0); bl = __shfl(bl, 0);
    stop += bv;
    if (bi == y) intop = 1;
    if (lane == bl) v = -INFINITY;
  }

  if (lane == 0) {
    const float lse = M + logf(S);
    const float loss = intop ? (13.f * lse - LY - 2.f * stop)
                             : (15.f * lse - 3.f * LY - 2.f * stop);
    atomicAdd(out, loss * (1.0f / 128.0f));
  }
}

// ---------------------------------------------------------------------------
// em_update: labels staged to LDS. Block i acts only if i is the first
// occurrence of label[i]; walks the duplicate chain sequentially (exact fp32).
// ---------------------------------------------------------------------------
__global__ __launch_bounds__(256) void em_update(
    const float* __restrict__ inp,
    const int*   __restrict__ label,
    const float* __restrict__ em,
    const int*   __restrict__ epoch,
    float*       __restrict__ out_em)
{
  __shared__ int lbl[B_];
  __shared__ float red[4];
  const int t = threadIdx.x;
  if (t < B_) lbl[t] = label[t];
  __syncthreads();

  const int i = blockIdx.x;
  const int y = lbl[i];
  for (int j = 0; j < i; ++j)
    if (lbl[j] == y) return;            // uniform: all threads agree

  const float alpha = 0.01f * (float)epoch[0];
  const int lane = t & 63, wave = t >> 6;

  float r[8];
  #pragma unroll
  for (int u = 0; u < 8; ++u) r[u] = em[(size_t)y * D_ + t + u * 256];

  for (int j = i; j < B_; ++j) {
    if (lbl[j] != y) continue;          // uniform branch
    const float* x = inp + j * D_;
    float ss = 0.f;
    #pragma unroll
    for (int u = 0; u < 8; ++u) {
      r[u] = alpha * r[u] + (1.f - alpha) * x[t + u * 256];
      ss += r[u] * r[u];
    }
    #pragma unroll
    for (int off = 32; off >= 1; off >>= 1) ss += __shfl_down(ss, off);
    if (lane == 0) red[wave] = ss;
    __syncthreads();
    const float inv = 1.f / sqrtf(red[0] + red[1] + red[2] + red[3]);
    #pragma unroll
    for (int u = 0; u < 8; ++u) r[u] *= inv;
    __syncthreads();                    // red[] reused next chain step
  }

  #pragma unroll
  for (int u = 0; u < 8; ++u) out_em[(size_t)y * D_ + t + u * 256] = r[u];
}

// ---------------------------------------------------------------------------
extern "C" void kernel_launch(void* const* d_in, const int* in_sizes, int n_in,
                              void* d_out, int out_size, void* d_ws, size_t ws_size,
                              hipStream_t stream) {
  const float* inp   = (const float*)d_in[0];
  const int*   label = (const int*)d_in[1];
  const float* em    = (const float*)d_in[2];
  const int*   epoch = (const int*)d_in[3];

  float* out    = (float*)d_out;
  float* out_em = out + 1;
  float* logits = (float*)d_ws;
  bf16*  apack  = (bf16*)((char*)d_ws + WS_APACK_OFF);
  float* part   = (float*)((char*)d_ws + WS_PART_OFF);

  hipMemsetAsync(d_out, 0, sizeof(float), stream);   // zero the loss slot

  pack_a        <<<dim3(128),        dim3(256), 0, stream>>>(inp, apack);
  gemm_logits   <<<dim3(NTILES),     dim3(256), 0, stream>>>(apack, em, logits, out_em);
  row_loss_part <<<dim3(B_ * NCHUNK),dim3(256), 0, stream>>>(logits, label, part);
  row_loss_merge<<<dim3(B_),         dim3(64),  0, stream>>>(part, label, out);
  em_update     <<<dim3(B_),         dim3(256), 0, stream>>>(inp, label, em, epoch, out_em);
}

// Round 4
// 362.270 us; speedup vs baseline: 1.2003x; 1.0704x over previous
//
#include <hip/hip_runtime.h>
#include <hip/hip_bf16.h>
#include <cstddef>

#define B_    128
#define D_    2048
#define C_    16522
#define BETA_INV 20.0f      // 1/0.05
#define LSTRIDE 16528       // padded logits row stride (floats)

#define NTILES 1033         // ceil(C/16)
#define NCHUNK 8
#define CHW    2066         // ceil(C/8)

typedef __bf16 bf16;
typedef bf16  bf16x8 __attribute__((ext_vector_type(8)));
typedef float f32x4  __attribute__((ext_vector_type(4)));

// ws layout (bytes):
//   logits : [0, 8462336)                128*16528*4
//   A_pack : [8462336, 8986624)          128*2048*2  bf16 fragment-ordered
//   part   : [8986624, 9052160)          128*8*16*4  row_loss partials
#define WS_APACK_OFF 8462336
#define WS_PART_OFF  8986624

// ---------------------------------------------------------------------------
// pack_a: inputs [128,2048] fp32 -> bf16 in MFMA A-fragment order.
// frag f = mtile*64 + kstep; element tid = f*64 + lane (bf16x8 each).
// A[m = mtile*16 + (lane&15)][k = kstep*32 + (lane>>4)*8 + j]
// ---------------------------------------------------------------------------
__global__ __launch_bounds__(256) void pack_a(const float* __restrict__ inp,
                                              bf16* __restrict__ ap) {
  const int tid  = blockIdx.x * 256 + threadIdx.x;   // 0..32767
  const int lane = tid & 63;
  const int ks   = (tid >> 6) & 63;
  const int mt   = tid >> 12;
  const int row  = mt * 16 + (lane & 15);
  const int col  = ks * 32 + (lane >> 4) * 8;
  const f32x4 v0 = *(const f32x4*)(inp + row * D_ + col);
  const f32x4 v1 = *(const f32x4*)(inp + row * D_ + col + 4);
  bf16x8 b;
  b[0] = (bf16)v0[0]; b[1] = (bf16)v0[1]; b[2] = (bf16)v0[2]; b[3] = (bf16)v0[3];
  b[4] = (bf16)v1[0]; b[5] = (bf16)v1[1]; b[6] = (bf16)v1[2]; b[7] = (bf16)v1[3];
  ((bf16x8*)ap)[tid] = b;
}

// ---------------------------------------------------------------------------
// gemm: 4 waves per block, one 16-row n-tile of em per BLOCK.
// Wave w owns m-tiles {w, w+4} -> acc is 2 f32x4.
// Round-4 change: k-loop is PURE READ. Rounds 0/2/3 all pinned at
// ~1.45 TB/s with copy-through stores inside the k-loop (stores share
// vmcnt with loads and retire in issue order, so each iteration's
// s_waitcnt transitively waits on an HBM store; plus fine R/W interleave
// costs DRAM turnaround). The em->out_em copy is now phase 2 of the same
// kernel: re-reads are L3-hits (em streamed through the 256MB L3 by the
// k-loop; round-3 FETCH=81MB<135MB proves partial L3 residency), so HBM
// traffic stays at the fused ideal (~278 MB) while stores are fully
// decoupled from the MFMA wait chain.
// ---------------------------------------------------------------------------
__global__ __launch_bounds__(256, 4) void gemm_logits(
    const bf16*  __restrict__ ap,
    const float* __restrict__ em,
    float*       __restrict__ logits,
    float*       __restrict__ out_em)
{
  const int lane = threadIdx.x & 63;
  const int w    = threadIdx.x >> 6;       // wave id 0..3
  const int ml   = lane & 15;
  const int quad = lane >> 4;
  const int n0   = blockIdx.x * 16;
  const int r    = n0 + ml;
  const bool valid = r < C_;

  const float* bp = em + (size_t)(valid ? r : 0) * D_ + quad * 8;
  const bf16x8* af = (const bf16x8*)ap;
  const int mt0 = w, mt1 = w + 4;

  f32x4 acc0 = {}, acc1 = {};

  // prologue: iterations 0 and 1 in flight
  f32x4 e0a = *(const f32x4*)(bp);
  f32x4 e0b = *(const f32x4*)(bp + 4);
  bf16x8 A00 = af[(mt0 * 64 + 0) * 64 + lane];
  bf16x8 A10 = af[(mt1 * 64 + 0) * 64 + lane];
  f32x4 e1a = *(const f32x4*)(bp + 32);
  f32x4 e1b = *(const f32x4*)(bp + 36);
  bf16x8 A01 = af[(mt0 * 64 + 1) * 64 + lane];
  bf16x8 A11 = af[(mt1 * 64 + 1) * 64 + lane];

  #pragma unroll 2
  for (int ks = 0; ks < 62; ++ks) {
    // prefetch ks+2
    const f32x4 e2a = *(const f32x4*)(bp + (ks + 2) * 32);
    const f32x4 e2b = *(const f32x4*)(bp + (ks + 2) * 32 + 4);
    const bf16x8 A02 = af[(mt0 * 64 + ks + 2) * 64 + lane];
    const bf16x8 A12 = af[(mt1 * 64 + ks + 2) * 64 + lane];
    // consume ks
    bf16x8 bv;
    bv[0] = (bf16)e0a[0]; bv[1] = (bf16)e0a[1]; bv[2] = (bf16)e0a[2]; bv[3] = (bf16)e0a[3];
    bv[4] = (bf16)e0b[0]; bv[5] = (bf16)e0b[1]; bv[6] = (bf16)e0b[2]; bv[7] = (bf16)e0b[3];
    acc0 = __builtin_amdgcn_mfma_f32_16x16x32_bf16(A00, bv, acc0, 0, 0, 0);
    acc1 = __builtin_amdgcn_mfma_f32_16x16x32_bf16(A10, bv, acc1, 0, 0, 0);
    // rotate
    e0a = e1a; e0b = e1b; e1a = e2a; e1b = e2b;
    A00 = A01; A01 = A02; A10 = A11; A11 = A12;
  }
  // epilogue ks=62
  {
    bf16x8 bv;
    bv[0] = (bf16)e0a[0]; bv[1] = (bf16)e0a[1]; bv[2] = (bf16)e0a[2]; bv[3] = (bf16)e0a[3];
    bv[4] = (bf16)e0b[0]; bv[5] = (bf16)e0b[1]; bv[6] = (bf16)e0b[2]; bv[7] = (bf16)e0b[3];
    acc0 = __builtin_amdgcn_mfma_f32_16x16x32_bf16(A00, bv, acc0, 0, 0, 0);
    acc1 = __builtin_amdgcn_mfma_f32_16x16x32_bf16(A10, bv, acc1, 0, 0, 0);
  }
  // epilogue ks=63
  {
    bf16x8 bv;
    bv[0] = (bf16)e1a[0]; bv[1] = (bf16)e1a[1]; bv[2] = (bf16)e1a[2]; bv[3] = (bf16)e1a[3];
    bv[4] = (bf16)e1b[0]; bv[5] = (bf16)e1b[1]; bv[6] = (bf16)e1b[2]; bv[7] = (bf16)e1b[3];
    acc0 = __builtin_amdgcn_mfma_f32_16x16x32_bf16(A01, bv, acc0, 0, 0, 0);
    acc1 = __builtin_amdgcn_mfma_f32_16x16x32_bf16(A11, bv, acc1, 0, 0, 0);
  }

  if (valid) {
    #pragma unroll
    for (int reg = 0; reg < 4; ++reg) {
      const int row0 = mt0 * 16 + quad * 4 + reg;
      const int row1 = mt1 * 16 + quad * 4 + reg;
      logits[row0 * LSTRIDE + r] = acc0[reg] * BETA_INV;
      logits[row1 * LSTRIDE + r] = acc1[reg] * BETA_INV;
    }
  }

  // phase 2: copy-through em -> out_em for this block's 16 rows.
  // Reads are L3-hits (just streamed); writes are a pure burst with no
  // dependent MFMA waits behind them.
  const int t = threadIdx.x;
  #pragma unroll
  for (int rr = 0; rr < 16; ++rr) {
    const int row = n0 + rr;
    if (row >= C_) break;
    const f32x4* src = (const f32x4*)(em + (size_t)row * D_);
    f32x4*       dst = (f32x4*)(out_em + (size_t)row * D_);
    dst[t]       = src[t];
    dst[t + 256] = src[t + 256];
  }
}

// ---------------------------------------------------------------------------
// row_loss phase A: grid = 128 rows x 8 chunks. Partial online-lse + top-6
// + label logit per chunk -> part[(b*8+c)*16].
// ---------------------------------------------------------------------------
__global__ __launch_bounds__(256) void row_loss_part(
    const float* __restrict__ logits,
    const int*   __restrict__ label,
    float*       __restrict__ part)
{
  const int b = blockIdx.x >> 3;
  const int c = blockIdx.x & 7;
  const int t = threadIdx.x;
  const int lo = c * CHW;
  const int hi = (lo + CHW < C_) ? lo + CHW : C_;
  const float* row = logits + b * LSTRIDE;
  const int y = label[b];

  float m = -INFINITY, s = 0.f, ly = -INFINITY;
  float tv[6]; int ti[6];
  #pragma unroll
  for (int q = 0; q < 6; ++q) { tv[q] = -INFINITY; ti[q] = -1; }

  for (int i = lo + t; i < hi; i += 256) {
    const float v = row[i];
    if (v > m) { s = s * __expf(m - v) + 1.f; m = v; }
    else       { s += __expf(v - m); }
    if (i == y) ly = v;
    if (v > tv[5]) {
      tv[5] = v; ti[5] = i;
      #pragma unroll
      for (int q = 5; q > 0; --q)
        if (tv[q] > tv[q - 1]) {
          const float fv = tv[q]; tv[q] = tv[q - 1]; tv[q - 1] = fv;
          const int   fi = ti[q]; ti[q] = ti[q - 1]; ti[q - 1] = fi;
        }
    }
  }

  __shared__ float rm[256], rs[256];
  __shared__ float cv[1536];
  __shared__ int   ci[1536];
  __shared__ float sly;

  rm[t] = m; rs[t] = s;
  #pragma unroll
  for (int q = 0; q < 6; ++q) { cv[t * 6 + q] = tv[q]; ci[t * 6 + q] = ti[q]; }
  if (t == 0) sly = -INFINITY;
  __syncthreads();
  if (ly != -INFINITY) sly = ly;

  for (int off = 128; off >= 1; off >>= 1) {
    if (t < off) {
      const float m2 = rm[t + off], s2 = rs[t + off];
      const float M = fmaxf(rm[t], m2);
      rs[t] = rs[t] * __expf(rm[t] - M) + s2 * __expf(m2 - M);
      rm[t] = M;
    }
    __syncthreads();
  }

  if (t < 64) {   // wave 0: top-6 of 1536 candidates
    float otv[6]; int oti[6];
    for (int rr = 0; rr < 6; ++rr) {
      float bv = -INFINITY; int bi = -1, bs = -1;
      for (int u = 0; u < 24; ++u) {
        const int slot = t * 24 + u;
        const float v = cv[slot];
        if (v > bv) { bv = v; bi = ci[slot]; bs = slot; }
      }
      #pragma unroll
      for (int off = 32; off >= 1; off >>= 1) {
        const float ov = __shfl_down(bv, off);
        const int   oi = __shfl_down(bi, off);
        const int   os = __shfl_down(bs, off);
        if (ov > bv) { bv = ov; bi = oi; bs = os; }
      }
      bv = __shfl(bv, 0); bi = __shfl(bi, 0); bs = __shfl(bs, 0);
      if (bs >= t * 24 && bs < (t + 1) * 24) cv[bs] = -INFINITY;
      otv[rr] = bv; oti[rr] = bi;
    }
    if (t == 0) {
      float* p = part + (size_t)(b * 8 + c) * 16;
      p[0] = rm[0]; p[1] = rs[0]; p[2] = sly;
      #pragma unroll
      for (int q = 0; q < 6; ++q) { p[4 + q] = otv[q]; ((int*)p)[10 + q] = oti[q]; }
    }
  }
}

// ---------------------------------------------------------------------------
// row_loss merge: 128 blocks x 64 threads. Merge 8 chunk-partials, compute
// loss, atomicAdd into out[0].
// ---------------------------------------------------------------------------
__global__ __launch_bounds__(64) void row_loss_merge(
    const float* __restrict__ part,
    const int*   __restrict__ label,
    float*       __restrict__ out)
{
  const int b = blockIdx.x;
  const int lane = threadIdx.x;
  const int y = label[b];

  float m = -INFINITY, s = 0.f, ly = -INFINITY;
  if (lane < 8) {
    const float* p = part + (size_t)(b * 8 + lane) * 16;
    m = p[0]; s = p[1]; ly = p[2];
  }
  float M = m, LY = ly;
  #pragma unroll
  for (int off = 32; off >= 1; off >>= 1) {
    M  = fmaxf(M,  __shfl_down(M,  off));
    LY = fmaxf(LY, __shfl_down(LY, off));
  }
  M = __shfl(M, 0); LY = __shfl(LY, 0);
  float contrib = (lane < 8) ? s * __expf(m - M) : 0.f;
  #pragma unroll
  for (int off = 32; off >= 1; off >>= 1) contrib += __shfl_down(contrib, off);
  const float S = __shfl(contrib, 0);

  float v = -INFINITY; int idx = -1;
  if (lane < 48) {
    const float* p = part + (size_t)(b * 8 + lane / 6) * 16;
    v   = p[4 + lane % 6];
    idx = ((const int*)p)[10 + lane % 6];
  }
  float stop = 0.f; int intop = 0;
  for (int rr = 0; rr < 6; ++rr) {
    float bv = v; int bi = idx, bl = lane;
    #pragma unroll
    for (int off = 32; off >= 1; off >>= 1) {
      const float ov = __shfl_down(bv, off);
      const int   oi = __shfl_down(bi, off);
      const int   ol = __shfl_down(bl, off);
      if (ov > bv) { bv = ov; bi = oi; bl = ol; }
    }
    bv = __shfl(bv, 0); bi = __shfl(bi, 0); bl = __shfl(bl, 0);
    stop += bv;
    if (bi == y) intop = 1;
    if (lane == bl) v = -INFINITY;
  }

  if (lane == 0) {
    const float lse = M + logf(S);
    const float loss = intop ? (13.f * lse - LY - 2.f * stop)
                             : (15.f * lse - 3.f * LY - 2.f * stop);
    atomicAdd(out, loss * (1.0f / 128.0f));
  }
}

// ---------------------------------------------------------------------------
// em_update: labels staged to LDS. Block i acts only if i is the first
// occurrence of label[i]; walks the duplicate chain sequentially (exact fp32).
// ---------------------------------------------------------------------------
__global__ __launch_bounds__(256) void em_update(
    const float* __restrict__ inp,
    const int*   __restrict__ label,
    const float* __restrict__ em,
    const int*   __restrict__ epoch,
    float*       __restrict__ out_em)
{
  __shared__ int lbl[B_];
  __shared__ float red[4];
  const int t = threadIdx.x;
  if (t < B_) lbl[t] = label[t];
  __syncthreads();

  const int i = blockIdx.x;
  const int y = lbl[i];
  for (int j = 0; j < i; ++j)
    if (lbl[j] == y) return;            // uniform: all threads agree

  const float alpha = 0.01f * (float)epoch[0];
  const int lane = t & 63, wave = t >> 6;

  float r[8];
  #pragma unroll
  for (int u = 0; u < 8; ++u) r[u] = em[(size_t)y * D_ + t + u * 256];

  for (int j = i; j < B_; ++j) {
    if (lbl[j] != y) continue;          // uniform branch
    const float* x = inp + j * D_;
    float ss = 0.f;
    #pragma unroll
    for (int u = 0; u < 8; ++u) {
      r[u] = alpha * r[u] + (1.f - alpha) * x[t + u * 256];
      ss += r[u] * r[u];
    }
    #pragma unroll
    for (int off = 32; off >= 1; off >>= 1) ss += __shfl_down(ss, off);
    if (lane == 0) red[wave] = ss;
    __syncthreads();
    const float inv = 1.f / sqrtf(red[0] + red[1] + red[2] + red[3]);
    #pragma unroll
    for (int u = 0; u < 8; ++u) r[u] *= inv;
    __syncthreads();                    // red[] reused next chain step
  }

  #pragma unroll
  for (int u = 0; u < 8; ++u) out_em[(size_t)y * D_ + t + u * 256] = r[u];
}

// ---------------------------------------------------------------------------
extern "C" void kernel_launch(void* const* d_in, const int* in_sizes, int n_in,
                              void* d_out, int out_size, void* d_ws, size_t ws_size,
                              hipStream_t stream) {
  const float* inp   = (const float*)d_in[0];
  const int*   label = (const int*)d_in[1];
  const float* em    = (const float*)d_in[2];
  const int*   epoch = (const int*)d_in[3];

  float* out    = (float*)d_out;
  float* out_em = out + 1;
  float* logits = (float*)d_ws;
  bf16*  apack  = (bf16*)((char*)d_ws + WS_APACK_OFF);
  float* part   = (float*)((char*)d_ws + WS_PART_OFF);

  hipMemsetAsync(d_out, 0, sizeof(float), stream);   // zero the loss slot

  pack_a        <<<dim3(128),        dim3(256), 0, stream>>>(inp, apack);
  gemm_logits   <<<dim3(NTILES),     dim3(256), 0, stream>>>(apack, em, logits, out_em);
  row_loss_part <<<dim3(B_ * NCHUNK),dim3(256), 0, stream>>>(logits, label, part);
  row_loss_merge<<<dim3(B_),         dim3(64),  0, stream>>>(part, label, out);
  em_update     <<<dim3(B_),         dim3(256), 0, stream>>>(inp, label, em, epoch, out_em);
}

// Round 5
// 322.986 us; speedup vs baseline: 1.3463x; 1.1216x over previous
//
#include <hip/hip_runtime.h>
#include <hip/hip_bf16.h>
#include <cstddef>

#define B_    128
#define D_    2048
#define C_    16522
#define BETA_INV 20.0f      // 1/0.05
#define LSTRIDE 16528       // padded logits row stride (floats)

#define NTILES 1033         // ceil(C/16)
#define NCHUNK 8
#define CHW    2066         // ceil(C/8)

typedef __bf16 bf16;
typedef bf16  bf16x8 __attribute__((ext_vector_type(8)));
typedef bf16  bf16x4 __attribute__((ext_vector_type(4)));
typedef float f32x4  __attribute__((ext_vector_type(4)));

// ws layout (bytes):
//   logits : [0, 8462336)                128*16528*4
//   A_pack : [8462336, 8986624)          128*2048*2  bf16 fragment-ordered
//   part   : [8986624, 9052160)          128*8*16*4  row_loss partials
#define WS_APACK_OFF 8462336
#define WS_PART_OFF  8986624

// ---------------------------------------------------------------------------
// pack_a: inputs [128,2048] fp32 -> bf16 in MFMA A-fragment order.
// frag f = mtile*64 + kstep; element tid = f*64 + lane (bf16x8 each).
// A[m = mtile*16 + (lane&15)][k = kstep*32 + (lane>>4)*8 + j]
// ---------------------------------------------------------------------------
__global__ __launch_bounds__(256) void pack_a(const float* __restrict__ inp,
                                              bf16* __restrict__ ap) {
  const int tid  = blockIdx.x * 256 + threadIdx.x;   // 0..32767
  const int lane = tid & 63;
  const int ks   = (tid >> 6) & 63;
  const int mt   = tid >> 12;
  const int row  = mt * 16 + (lane & 15);
  const int col  = ks * 32 + (lane >> 4) * 8;
  const f32x4 v0 = *(const f32x4*)(inp + row * D_ + col);
  const f32x4 v1 = *(const f32x4*)(inp + row * D_ + col + 4);
  bf16x8 b;
  b[0] = (bf16)v0[0]; b[1] = (bf16)v0[1]; b[2] = (bf16)v0[2]; b[3] = (bf16)v0[3];
  b[4] = (bf16)v1[0]; b[5] = (bf16)v1[1]; b[6] = (bf16)v1[2]; b[7] = (bf16)v1[3];
  ((bf16x8*)ap)[tid] = b;
}

static __device__ __forceinline__ bf16x4 cvt4(const f32x4 v) {
  bf16x4 h;
  h[0] = (bf16)v[0]; h[1] = (bf16)v[1]; h[2] = (bf16)v[2]; h[3] = (bf16)v[3];
  return h;
}

// ---------------------------------------------------------------------------
// gemm, round 5: LDS-staged. Round-4 post-mortem: 4 variants all pinned at
// 1.4-1.9 TB/s regardless of occupancy/stores because each direct em load
// instruction gathers 16 discontiguous rows (16 cache lines, 64B used each).
// New structure: 512 threads (8 waves), n-tile=16 rows, BK=256 floats.
//  - staging: per chunk each thread does TWO fully-coalesced f32x4 loads
//    (each wave covers a contiguous 1KB of one em row), converts to bf16,
//    ds_writes into padded [16][264] bf16 tile (uniform bank use).
//  - double-buffered LDS, one barrier/chunk; chunk k+1 loads issued before
//    computing chunk k (loads get the whole compute phase of slack).
//  - inner loop per MFMA k-step: 1 ds_read_b128 + 1 L2-hot A-frag load +
//    1 MFMA; zero VALU converts in the hot loop.
//  - LDS 16.9KB/block -> 4 blocks/CU * 8 waves = 32 waves/CU.
// Phase 2 (copy-through em->out_em) unchanged from round 4.
// ---------------------------------------------------------------------------
__global__ __launch_bounds__(512, 8) void gemm_logits(
    const bf16*  __restrict__ ap,
    const float* __restrict__ em,
    float*       __restrict__ logits,
    float*       __restrict__ out_em)
{
  __shared__ bf16 sbuf[2][16][264];    // 264 = 256 + 8 pad (bank spread)

  const int t    = threadIdx.x;
  const int lane = t & 63;
  const int w    = t >> 6;             // wave id 0..7 == m-tile index
  const int ml   = lane & 15;
  const int quad = lane >> 4;
  const int n0   = blockIdx.x * 16;
  const int r    = n0 + ml;
  const bool valid = r < C_;

  // staging mapping: thread t loads rows {srow, srow+8}, float cols [scol,scol+4)
  const int srow = t >> 6;             // 0..7
  const int scol = (t & 63) * 4;       // 0..252
  const int ra = (n0 + srow     < C_) ? (n0 + srow)     : (C_ - 1);
  const int rb = (n0 + srow + 8 < C_) ? (n0 + srow + 8) : (C_ - 1);
  const float* sa = em + (size_t)ra * D_ + scol;
  const float* sb = em + (size_t)rb * D_ + scol;

  const bf16x8* af = (const bf16x8*)ap;
  f32x4 acc = {};

  // prologue: stage chunk 0
  {
    const f32x4 g0 = *(const f32x4*)(sa);
    const f32x4 g1 = *(const f32x4*)(sb);
    *(bf16x4*)&sbuf[0][srow][scol]     = cvt4(g0);
    *(bf16x4*)&sbuf[0][srow + 8][scol] = cvt4(g1);
  }
  __syncthreads();

  for (int kc = 0; kc < 8; ++kc) {
    // issue next-chunk loads early (vmcnt slack = whole compute phase)
    f32x4 g0 = {}, g1 = {};
    if (kc < 7) {
      g0 = *(const f32x4*)(sa + (kc + 1) * 256);
      g1 = *(const f32x4*)(sb + (kc + 1) * 256);
    }

    // compute chunk kc from sbuf[kc&1]: 8 MFMA k-steps, 1-deep rotation
    const bf16*   bbase = &sbuf[kc & 1][ml][quad * 8];
    const bf16x8* apc   = af + (size_t)(w * 64 + kc * 8) * 64 + lane;
    bf16x8 b0 = *(const bf16x8*)(bbase);
    bf16x8 a0 = apc[0];
    #pragma unroll
    for (int kk = 0; kk < 7; ++kk) {
      const bf16x8 b1 = *(const bf16x8*)(bbase + (kk + 1) * 32);
      const bf16x8 a1 = apc[(size_t)(kk + 1) * 64];
      acc = __builtin_amdgcn_mfma_f32_16x16x32_bf16(a0, b0, acc, 0, 0, 0);
      b0 = b1; a0 = a1;
    }
    acc = __builtin_amdgcn_mfma_f32_16x16x32_bf16(a0, b0, acc, 0, 0, 0);

    // write chunk kc+1 into the other buffer (all waves have finished
    // reading it: the barrier at the end of iter kc-1 guarantees that)
    if (kc < 7) {
      *(bf16x4*)&sbuf[(kc + 1) & 1][srow][scol]     = cvt4(g0);
      *(bf16x4*)&sbuf[(kc + 1) & 1][srow + 8][scol] = cvt4(g1);
    }
    __syncthreads();
  }

  // logits epilogue: wave w owns m-tile w
  if (valid) {
    #pragma unroll
    for (int reg = 0; reg < 4; ++reg) {
      const int row = w * 16 + quad * 4 + reg;
      logits[row * LSTRIDE + r] = acc[reg] * BETA_INV;
    }
  }

  // phase 2: copy-through em -> out_em for this block's 16 rows.
  // Reads are L3-hits (just streamed); writes are a pure burst with no
  // dependent MFMA waits behind them.
  for (int rr = 0; rr < 16; ++rr) {
    const int row = n0 + rr;
    if (row >= C_) break;
    const f32x4* src = (const f32x4*)(em + (size_t)row * D_);
    f32x4*       dst = (f32x4*)(out_em + (size_t)row * D_);
    dst[t] = src[t];
  }
}

// ---------------------------------------------------------------------------
// row_loss phase A: grid = 128 rows x 8 chunks. Partial online-lse + top-6
// + label logit per chunk -> part[(b*8+c)*16].
// ---------------------------------------------------------------------------
__global__ __launch_bounds__(256) void row_loss_part(
    const float* __restrict__ logits,
    const int*   __restrict__ label,
    float*       __restrict__ part)
{
  const int b = blockIdx.x >> 3;
  const int c = blockIdx.x & 7;
  const int t = threadIdx.x;
  const int lo = c * CHW;
  const int hi = (lo + CHW < C_) ? lo + CHW : C_;
  const float* row = logits + b * LSTRIDE;
  const int y = label[b];

  float m = -INFINITY, s = 0.f, ly = -INFINITY;
  float tv[6]; int ti[6];
  #pragma unroll
  for (int q = 0; q < 6; ++q) { tv[q] = -INFINITY; ti[q] = -1; }

  for (int i = lo + t; i < hi; i += 256) {
    const float v = row[i];
    if (v > m) { s = s * __expf(m - v) + 1.f; m = v; }
    else       { s += __expf(v - m); }
    if (i == y) ly = v;
    if (v > tv[5]) {
      tv[5] = v; ti[5] = i;
      #pragma unroll
      for (int q = 5; q > 0; --q)
        if (tv[q] > tv[q - 1]) {
          const float fv = tv[q]; tv[q] = tv[q - 1]; tv[q - 1] = fv;
          const int   fi = ti[q]; ti[q] = ti[q - 1]; ti[q - 1] = fi;
        }
    }
  }

  __shared__ float rm[256], rs[256];
  __shared__ float cv[1536];
  __shared__ int   ci[1536];
  __shared__ float sly;

  rm[t] = m; rs[t] = s;
  #pragma unroll
  for (int q = 0; q < 6; ++q) { cv[t * 6 + q] = tv[q]; ci[t * 6 + q] = ti[q]; }
  if (t == 0) sly = -INFINITY;
  __syncthreads();
  if (ly != -INFINITY) sly = ly;

  for (int off = 128; off >= 1; off >>= 1) {
    if (t < off) {
      const float m2 = rm[t + off], s2 = rs[t + off];
      const float M = fmaxf(rm[t], m2);
      rs[t] = rs[t] * __expf(rm[t] - M) + s2 * __expf(m2 - M);
      rm[t] = M;
    }
    __syncthreads();
  }

  if (t < 64) {   // wave 0: top-6 of 1536 candidates
    float otv[6]; int oti[6];
    for (int rr = 0; rr < 6; ++rr) {
      float bv = -INFINITY; int bi = -1, bs = -1;
      for (int u = 0; u < 24; ++u) {
        const int slot = t * 24 + u;
        const float v = cv[slot];
        if (v > bv) { bv = v; bi = ci[slot]; bs = slot; }
      }
      #pragma unroll
      for (int off = 32; off >= 1; off >>= 1) {
        const float ov = __shfl_down(bv, off);
        const int   oi = __shfl_down(bi, off);
        const int   os = __shfl_down(bs, off);
        if (ov > bv) { bv = ov; bi = oi; bs = os; }
      }
      bv = __shfl(bv, 0); bi = __shfl(bi, 0); bs = __shfl(bs, 0);
      if (bs >= t * 24 && bs < (t + 1) * 24) cv[bs] = -INFINITY;
      otv[rr] = bv; oti[rr] = bi;
    }
    if (t == 0) {
      float* p = part + (size_t)(b * 8 + c) * 16;
      p[0] = rm[0]; p[1] = rs[0]; p[2] = sly;
      #pragma unroll
      for (int q = 0; q < 6; ++q) { p[4 + q] = otv[q]; ((int*)p)[10 + q] = oti[q]; }
    }
  }
}

// ---------------------------------------------------------------------------
// row_loss merge: 128 blocks x 64 threads. Merge 8 chunk-partials, compute
// loss, atomicAdd into out[0].
// ---------------------------------------------------------------------------
__global__ __launch_bounds__(64) void row_loss_merge(
    const float* __restrict__ part,
    const int*   __restrict__ label,
    float*       __restrict__ out)
{
  const int b = blockIdx.x;
  const int lane = threadIdx.x;
  const int y = label[b];

  float m = -INFINITY, s = 0.f, ly = -INFINITY;
  if (lane < 8) {
    const float* p = part + (size_t)(b * 8 + lane) * 16;
    m = p[0]; s = p[1]; ly = p[2];
  }
  float M = m, LY = ly;
  #pragma unroll
  for (int off = 32; off >= 1; off >>= 1) {
    M  = fmaxf(M,  __shfl_down(M,  off));
    LY = fmaxf(LY, __shfl_down(LY, off));
  }
  M = __shfl(M, 0); LY = __shfl(LY, 0);
  float contrib = (lane < 8) ? s * __expf(m - M) : 0.f;
  #pragma unroll
  for (int off = 32; off >= 1; off >>= 1) contrib += __shfl_down(contrib, off);
  const float S = __shfl(contrib, 0);

  float v = -INFINITY; int idx = -1;
  if (lane < 48) {
    const float* p = part + (size_t)(b * 8 + lane / 6) * 16;
    v   = p[4 + lane % 6];
    idx = ((const int*)p)[10 + lane % 6];
  }
  float stop = 0.f; int intop = 0;
  for (int rr = 0; rr < 6; ++rr) {
    float bv = v; int bi = idx, bl = lane;
    #pragma unroll
    for (int off = 32; off >= 1; off >>= 1) {
      const float ov = __shfl_down(bv, off);
      const int   oi = __shfl_down(bi, off);
      const int   ol = __shfl_down(bl, off);
      if (ov > bv) { bv = ov; bi = oi; bl = ol; }
    }
    bv = __shfl(bv, 0); bi = __shfl(bi, 0); bl = __shfl(bl, 0);
    stop += bv;
    if (bi == y) intop = 1;
    if (lane == bl) v = -INFINITY;
  }

  if (lane == 0) {
    const float lse = M + logf(S);
    const float loss = intop ? (13.f * lse - LY - 2.f * stop)
                             : (15.f * lse - 3.f * LY - 2.f * stop);
    atomicAdd(out, loss * (1.0f / 128.0f));
  }
}

// ---------------------------------------------------------------------------
// em_update: labels staged to LDS. Block i acts only if i is the first
// occurrence of label[i]; walks the duplicate chain sequentially (exact fp32).
// ---------------------------------------------------------------------------
__global__ __launch_bounds__(256) void em_update(
    const float* __restrict__ inp,
    const int*   __restrict__ label,
    const float* __restrict__ em,
    const int*   __restrict__ epoch,
    float*       __restrict__ out_em)
{
  __shared__ int lbl[B_];
  __shared__ float red[4];
  const int t = threadIdx.x;
  if (t < B_) lbl[t] = label[t];
  __syncthreads();

  const int i = blockIdx.x;
  const int y = lbl[i];
  for (int j = 0; j < i; ++j)
    if (lbl[j] == y) return;            // uniform: all threads agree

  const float alpha = 0.01f * (float)epoch[0];
  const int lane = t & 63, wave = t >> 6;

  float r[8];
  #pragma unroll
  for (int u = 0; u < 8; ++u) r[u] = em[(size_t)y * D_ + t + u * 256];

  for (int j = i; j < B_; ++j) {
    if (lbl[j] != y) continue;          // uniform branch
    const float* x = inp + j * D_;
    float ss = 0.f;
    #pragma unroll
    for (int u = 0; u < 8; ++u) {
      r[u] = alpha * r[u] + (1.f - alpha) * x[t + u * 256];
      ss += r[u] * r[u];
    }
    #pragma unroll
    for (int off = 32; off >= 1; off >>= 1) ss += __shfl_down(ss, off);
    if (lane == 0) red[wave] = ss;
    __syncthreads();
    const float inv = 1.f / sqrtf(red[0] + red[1] + red[2] + red[3]);
    #pragma unroll
    for (int u = 0; u < 8; ++u) r[u] *= inv;
    __syncthreads();                    // red[] reused next chain step
  }

  #pragma unroll
  for (int u = 0; u < 8; ++u) out_em[(size_t)y * D_ + t + u * 256] = r[u];
}

// ---------------------------------------------------------------------------
extern "C" void kernel_launch(void* const* d_in, const int* in_sizes, int n_in,
                              void* d_out, int out_size, void* d_ws, size_t ws_size,
                              hipStream_t stream) {
  const float* inp   = (const float*)d_in[0];
  const int*   label = (const int*)d_in[1];
  const float* em    = (const float*)d_in[2];
  const int*   epoch = (const int*)d_in[3];

  float* out    = (float*)d_out;
  float* out_em = out + 1;
  float* logits = (float*)d_ws;
  bf16*  apack  = (bf16*)((char*)d_ws + WS_APACK_OFF);
  float* part   = (float*)((char*)d_ws + WS_PART_OFF);

  hipMemsetAsync(d_out, 0, sizeof(float), stream);   // zero the loss slot

  pack_a        <<<dim3(128),        dim3(256), 0, stream>>>(inp, apack);
  gemm_logits   <<<dim3(NTILES),     dim3(512), 0, stream>>>(apack, em, logits, out_em);
  row_loss_part <<<dim3(B_ * NCHUNK),dim3(256), 0, stream>>>(logits, label, part);
  row_loss_merge<<<dim3(B_),         dim3(64),  0, stream>>>(part, label, out);
  em_update     <<<dim3(B_),         dim3(256), 0, stream>>>(inp, label, em, epoch, out_em);
}

// Round 6
// 305.181 us; speedup vs baseline: 1.4249x; 1.0583x over previous
//
#include <hip/hip_runtime.h>
#include <hip/hip_bf16.h>
#include <cstddef>

#define B_    128
#define D_    2048
#define C_    16522
#define BETA_INV 20.0f      // 1/0.05
#define LSTRIDE 16528       // padded logits row stride (floats)

#define NTILES 1033         // ceil(C/16)

typedef __bf16 bf16;
typedef bf16  bf16x8 __attribute__((ext_vector_type(8)));
typedef bf16  bf16x4 __attribute__((ext_vector_type(4)));
typedef float f32x4  __attribute__((ext_vector_type(4)));

// ws layout (bytes):
//   logits : [0, 8462336)                128*16528*4
//   A_pack : [8462336, 8986624)          128*2048*2  bf16 fragment-ordered
#define WS_APACK_OFF 8462336

// ---------------------------------------------------------------------------
// pack_a: inputs [128,2048] fp32 -> bf16 in MFMA A-fragment order.
// frag f = mtile*64 + kstep; element tid = f*64 + lane (bf16x8 each).
// A[m = mtile*16 + (lane&15)][k = kstep*32 + (lane>>4)*8 + j]
// Also zeroes the loss accumulator (replaces hipMemsetAsync; pack_a is
// stream-ordered before the tail kernel's atomicAdds).
// ---------------------------------------------------------------------------
__global__ __launch_bounds__(256) void pack_a(const float* __restrict__ inp,
                                              bf16* __restrict__ ap,
                                              float* __restrict__ out) {
  const int tid  = blockIdx.x * 256 + threadIdx.x;   // 0..32767
  if (tid == 0) out[0] = 0.f;
  const int lane = tid & 63;
  const int ks   = (tid >> 6) & 63;
  const int mt   = tid >> 12;
  const int row  = mt * 16 + (lane & 15);
  const int col  = ks * 32 + (lane >> 4) * 8;
  const f32x4 v0 = *(const f32x4*)(inp + row * D_ + col);
  const f32x4 v1 = *(const f32x4*)(inp + row * D_ + col + 4);
  bf16x8 b;
  b[0] = (bf16)v0[0]; b[1] = (bf16)v0[1]; b[2] = (bf16)v0[2]; b[3] = (bf16)v0[3];
  b[4] = (bf16)v1[0]; b[5] = (bf16)v1[1]; b[6] = (bf16)v1[2]; b[7] = (bf16)v1[3];
  ((bf16x8*)ap)[tid] = b;
}

static __device__ __forceinline__ bf16x4 cvt4(const f32x4 v) {
  bf16x4 h;
  h[0] = (bf16)v[0]; h[1] = (bf16)v[1]; h[2] = (bf16)v[2]; h[3] = (bf16)v[3];
  return h;
}

// ---------------------------------------------------------------------------
// gemm, round 6: single-barrier full-tile staging.
// Round-5 post-mortem: per-chunk barriers created a convoy — each 16KB
// chunk's loads had only one short compute phase of slack, then the whole
// block stalled on the slowest load, 8x per block (Little's law: ~1.7KB in
// flight per CU -> 2.6 TB/s). Now the ENTIRE 16x2048 B-tile is staged in
// one shot: 16 coalesced f32x4 loads per thread (2 passes of 8 in flight),
// bf16-convert, XOR-swizzled ds_write, ONE barrier, then 64 MFMA k-steps.
// The em->out_em copy-through is fused into staging (same registers), so
// the L3 re-read of round 4/5's phase 2 disappears.
// Swizzle: byte ^= (row&7)<<4 on both ds_write and ds_read (same involution
// of the column-byte within each row -> bijective, write/read consistent).
// LDS = 64 KB exactly -> 2 blocks/CU (16 waves/CU); __launch_bounds__(512,4)
// caps VGPR at 128 (staging peak is 8 f32x4 = 32 regs).
// ---------------------------------------------------------------------------
__global__ __launch_bounds__(512, 4) void gemm_logits(
    const bf16*  __restrict__ ap,
    const float* __restrict__ em,
    float*       __restrict__ logits,
    float*       __restrict__ out_em)
{
  __shared__ bf16 sB[16 * 2048];       // 64 KB, swizzled layout

  const int t    = threadIdx.x;
  const int lane = t & 63;
  const int w    = t >> 6;             // wave id 0..7 == m-tile index
  const int ml   = lane & 15;
  const int quad = lane >> 4;
  const int n0   = blockIdx.x * 16;
  const int r    = n0 + ml;
  const bool valid = r < C_;

  // ---- staging + fused copy-through: wave w handles rows w and w+8 ----
  #pragma unroll
  for (int half = 0; half < 2; ++half) {
    const int row = w + half * 8;
    const int gr  = (n0 + row < C_) ? (n0 + row) : (C_ - 1);
    const f32x4* src = (const f32x4*)(em + (size_t)gr * D_);
    f32x4 g[8];
    #pragma unroll
    for (int i = 0; i < 8; ++i) g[i] = src[lane + i * 64];   // 8 loads in flight
    const int swz = (row & 7) << 4;
    #pragma unroll
    for (int i = 0; i < 8; ++i) {
      const int byte = (row << 12) + (lane << 3) + (i << 9); // row*4096 + lane*8 + i*512
      *(bf16x4*)((char*)sB + (byte ^ swz)) = cvt4(g[i]);
    }
    if (n0 + row < C_) {
      f32x4* dst = (f32x4*)(out_em + (size_t)(n0 + row) * D_);
      #pragma unroll
      for (int i = 0; i < 8; ++i) dst[lane + i * 64] = g[i];
    }
  }
  __syncthreads();   // the ONLY barrier

  // ---- k-loop: 64 MFMA steps, B from LDS, A-frags from L2-hot A-pack ----
  f32x4 acc = {};
  const bf16x8* apc = (const bf16x8*)ap + (size_t)(w * 64) * 64 + lane;
  const char* sb = (const char*)sB;
  const int rbase = (ml << 12) + (quad << 4);   // ml*4096 + quad*16
  const int rswz  = (ml & 7) << 4;
  #pragma unroll 16
  for (int ks = 0; ks < 64; ++ks) {
    const bf16x8 bfrag = *(const bf16x8*)(sb + ((rbase + (ks << 6)) ^ rswz));
    acc = __builtin_amdgcn_mfma_f32_16x16x32_bf16(apc[(size_t)ks * 64], bfrag,
                                                  acc, 0, 0, 0);
  }

  if (valid) {
    #pragma unroll
    for (int reg = 0; reg < 4; ++reg) {
      const int row = w * 16 + quad * 4 + reg;
      logits[row * LSTRIDE + r] = acc[reg] * BETA_INV;
    }
  }
}

// ---------------------------------------------------------------------------
// tail: fused row_loss (blocks 0..127, one block per sample row, full-row
// scan — replaces part+merge and the part buffer) and em_update (blocks
// 128..255). Branch is block-uniform; shared arrays are per-path.
// ---------------------------------------------------------------------------
__global__ __launch_bounds__(256) void tail(
    const float* __restrict__ logits,
    const int*   __restrict__ label,
    const float* __restrict__ inp,
    const float* __restrict__ em,
    const int*   __restrict__ epoch,
    float*       __restrict__ out,
    float*       __restrict__ out_em)
{
  __shared__ float rm[256], rs[256];
  __shared__ float cv[1536];
  __shared__ int   ci[1536];
  __shared__ float sly;
  __shared__ int   lbl[B_];
  __shared__ float red[4];

  const int t = threadIdx.x;

  if (blockIdx.x < B_) {
    // ---------------- row_loss: full row b, online lse + top-6 ----------
    const int b = blockIdx.x;
    const float* row = logits + b * LSTRIDE;
    const int y = label[b];

    float m = -INFINITY, s = 0.f, ly = -INFINITY;
    float tv[6]; int ti[6];
    #pragma unroll
    for (int q = 0; q < 6; ++q) { tv[q] = -INFINITY; ti[q] = -1; }

    for (int i = t; i < C_; i += 256) {
      const float v = row[i];
      if (v > m) { s = s * __expf(m - v) + 1.f; m = v; }
      else       { s += __expf(v - m); }
      if (i == y) ly = v;
      if (v > tv[5]) {
        tv[5] = v; ti[5] = i;
        #pragma unroll
        for (int q = 5; q > 0; --q)
          if (tv[q] > tv[q - 1]) {
            const float fv = tv[q]; tv[q] = tv[q - 1]; tv[q - 1] = fv;
            const int   fi = ti[q]; ti[q] = ti[q - 1]; ti[q - 1] = fi;
          }
      }
    }

    rm[t] = m; rs[t] = s;
    #pragma unroll
    for (int q = 0; q < 6; ++q) { cv[t * 6 + q] = tv[q]; ci[t * 6 + q] = ti[q]; }
    if (t == 0) sly = -INFINITY;
    __syncthreads();
    if (ly != -INFINITY) sly = ly;

    for (int off = 128; off >= 1; off >>= 1) {
      if (t < off) {
        const float m2 = rm[t + off], s2 = rs[t + off];
        const float M = fmaxf(rm[t], m2);
        rs[t] = rs[t] * __expf(rm[t] - M) + s2 * __expf(m2 - M);
        rm[t] = M;
      }
      __syncthreads();
    }

    if (t < 64) {   // wave 0: top-6 of 1536 candidates
      float otv[6]; int oti[6];
      for (int rr = 0; rr < 6; ++rr) {
        float bv = -INFINITY; int bi = -1, bs = -1;
        for (int u = 0; u < 24; ++u) {
          const int slot = t * 24 + u;
          const float v = cv[slot];
          if (v > bv) { bv = v; bi = ci[slot]; bs = slot; }
        }
        #pragma unroll
        for (int off = 32; off >= 1; off >>= 1) {
          const float ov = __shfl_down(bv, off);
          const int   oi = __shfl_down(bi, off);
          const int   os = __shfl_down(bs, off);
          if (ov > bv) { bv = ov; bi = oi; bs = os; }
        }
        bv = __shfl(bv, 0); bi = __shfl(bi, 0); bs = __shfl(bs, 0);
        if (bs >= t * 24 && bs < (t + 1) * 24) cv[bs] = -INFINITY;
        otv[rr] = bv; oti[rr] = bi;
      }
      if (t == 0) {
        const float lse = rm[0] + logf(rs[0]);
        float stop = 0.f; int intop = 0;
        #pragma unroll
        for (int q = 0; q < 6; ++q) {
          stop += otv[q];
          if (oti[q] == y) intop = 1;
        }
        const float lyv = sly;
        const float loss = intop ? (13.f * lse - lyv - 2.f * stop)
                                 : (15.f * lse - 3.f * lyv - 2.f * stop);
        atomicAdd(out, loss * (1.0f / 128.0f));
      }
    }
  } else {
    // ---------------- em_update: sample i = blockIdx.x - 128 ------------
    if (t < B_) lbl[t] = label[t];
    __syncthreads();

    const int i = blockIdx.x - B_;
    const int y = lbl[i];
    for (int j = 0; j < i; ++j)
      if (lbl[j] == y) return;          // uniform: all threads agree

    const float alpha = 0.01f * (float)epoch[0];
    const int lane = t & 63, wave = t >> 6;

    float rreg[8];
    #pragma unroll
    for (int u = 0; u < 8; ++u) rreg[u] = em[(size_t)y * D_ + t + u * 256];

    for (int j = i; j < B_; ++j) {
      if (lbl[j] != y) continue;        // uniform branch
      const float* x = inp + j * D_;
      float ss = 0.f;
      #pragma unroll
      for (int u = 0; u < 8; ++u) {
        rreg[u] = alpha * rreg[u] + (1.f - alpha) * x[t + u * 256];
        ss += rreg[u] * rreg[u];
      }
      #pragma unroll
      for (int off = 32; off >= 1; off >>= 1) ss += __shfl_down(ss, off);
      if (lane == 0) red[wave] = ss;
      __syncthreads();
      const float inv = 1.f / sqrtf(red[0] + red[1] + red[2] + red[3]);
      #pragma unroll
      for (int u = 0; u < 8; ++u) rreg[u] *= inv;
      __syncthreads();                  // red[] reused next chain step
    }

    #pragma unroll
    for (int u = 0; u < 8; ++u) out_em[(size_t)y * D_ + t + u * 256] = rreg[u];
  }
}

// ---------------------------------------------------------------------------
extern "C" void kernel_launch(void* const* d_in, const int* in_sizes, int n_in,
                              void* d_out, int out_size, void* d_ws, size_t ws_size,
                              hipStream_t stream) {
  const float* inp   = (const float*)d_in[0];
  const int*   label = (const int*)d_in[1];
  const float* em    = (const float*)d_in[2];
  const int*   epoch = (const int*)d_in[3];

  float* out    = (float*)d_out;
  float* out_em = out + 1;
  float* logits = (float*)d_ws;
  bf16*  apack  = (bf16*)((char*)d_ws + WS_APACK_OFF);

  pack_a      <<<dim3(128),    dim3(256), 0, stream>>>(inp, apack, out);
  gemm_logits <<<dim3(NTILES), dim3(512), 0, stream>>>(apack, em, logits, out_em);
  tail        <<<dim3(2 * B_), dim3(256), 0, stream>>>(logits, label, inp, em,
                                                       epoch, out, out_em);
}